// Round 1
// baseline (685.816 us; speedup 1.0000x reference)
//
#include <hip/hip_runtime.h>

// Mypenalizer: out[i] = in_bounds(v) ? 0.01*exp(4.81*(1+v)) : 3.0, v = X[i*8+7]
// Memory-bound: must fetch all 512 MiB of X (needed column touches every 64B
// sector) + write 64 MiB. Floor ~91us at 6.3 TB/s achievable.

#define A_CONST 0.01f
#define B_CONST 4.81f
#define OOB_COST 3.0f

__device__ __forceinline__ float penalize(float v) {
    // v in-bounds iff 0 <= v <= 1
    bool ib = (v >= 0.0f) && (v <= 1.0f);
    float c = A_CONST * __expf(B_CONST * (1.0f + v));
    return ib ? c : OOB_COST;
}

__global__ __launch_bounds__(256) void penalizer_kernel(
        const float* __restrict__ X, float* __restrict__ out, int nrows) {
    int tid = blockIdx.x * blockDim.x + threadIdx.x;
    long i0 = (long)tid * 4;
    if (i0 + 3 < nrows) {
        // 4 strided scalar loads (only the needed column; stride 32B)
        float v0 = X[i0 * 8 + 7];
        float v1 = X[i0 * 8 + 15];
        float v2 = X[i0 * 8 + 23];
        float v3 = X[i0 * 8 + 31];
        float4 r;
        r.x = penalize(v0);
        r.y = penalize(v1);
        r.z = penalize(v2);
        r.w = penalize(v3);
        // coalesced 16B store
        *reinterpret_cast<float4*>(out + i0) = r;
    } else {
        for (int k = 0; k < 4; ++k) {
            long i = i0 + k;
            if (i < nrows) out[i] = penalize(X[i * 8 + 7]);
        }
    }
}

extern "C" void kernel_launch(void* const* d_in, const int* in_sizes, int n_in,
                              void* d_out, int out_size, void* d_ws, size_t ws_size,
                              hipStream_t stream) {
    const float* X = (const float*)d_in[0];
    float* out = (float*)d_out;
    int nrows = out_size;  // = in_sizes[0] / 8
    int threads_needed = (nrows + 3) / 4;
    int block = 256;
    int grid = (threads_needed + block - 1) / block;
    penalizer_kernel<<<grid, block, 0, stream>>>(X, out, nrows);
}